// Round 7
// baseline (158.285 us; speedup 1.0000x reference)
//
#include <hip/hip_runtime.h>
#include <hip/hip_fp16.h>
#include <math.h>

#define NN 1024

typedef _Float16 half8 __attribute__((ext_vector_type(8)));
typedef float f32x4 __attribute__((ext_vector_type(4)));

union H8U { uint4 u; half8 h; };

__device__ __forceinline__ unsigned short h_bits(float x) {
    _Float16 h = (_Float16)x;          // RNE
    unsigned short b;
    __builtin_memcpy(&b, &h, 2);
    return b;
}

// ---- prep: blocks [0,512): A' = z_c@W1c + b1 -> fp16 frag-order Aph;
//            B = z_d@W1d -> fp16 frag-order Bph.
//            blocks [512,514): W2 -> fp16 MFMA frag layout W2h.
__global__ void prep_kernel(const float* __restrict__ z_c, const float* __restrict__ z_d,
                            const float* __restrict__ W1, const float* __restrict__ b1,
                            const float* __restrict__ W2,
                            unsigned short* __restrict__ Aph,
                            unsigned short* __restrict__ Bph,
                            uint4* __restrict__ W2h) {
    if (blockIdx.x < 512) {
        int t = blockIdx.x * 256 + threadIdx.x;
        int sel = t >> 16;            // 0 -> A', 1 -> B
        int idx = t & 0xffff;
        int n = idx >> 6, h = idx & 63;
        const float* z = (sel ? z_d : z_c) + n * 64;
        const float* w = W1 + (sel ? 4096 : 0) + h;   // W1 (128,64) row-major
        float a0 = sel ? 0.f : b1[h], a1 = 0.f;
        #pragma unroll
        for (int k = 0; k < 64; k += 2) {
            a0 = fmaf(z[k],     w[k * 64],       a0);
            a1 = fmaf(z[k + 1], w[(k + 1) * 64], a1);
        }
        unsigned short val = h_bits(a0 + a1);   // fp32-exact matmul, one RNE to fp16
        int s = h >> 5, q = (h >> 3) & 3, e = h & 7;
        if (sel) {
            Bph[n * 64 + q * 16 + s * 8 + e] = val;
        } else {
            Aph[(n >> 4) * 1024 + (q * 16 + (n & 15)) * 16 + s * 8 + e] = val;
        }
    } else {
        int tt = (blockIdx.x - 512) * 256 + threadIdx.x;   // 0..511
        int f = tt >> 6, lane = tt & 63;                   // f = s*4 + t, 8 frags
        int s = f >> 2, t4 = f & 3, q = lane >> 4, l15 = lane & 15;
        int n = t4 * 16 + l15;
        unsigned w4[4];
        #pragma unroll
        for (int p = 0; p < 4; ++p) {
            int k = s * 32 + q * 8 + 2 * p;
            unsigned lo = h_bits(W2[k * 64 + n]);
            unsigned hi = h_bits(W2[(k + 1) * 64 + n]);
            w4[p] = lo | (hi << 16);
        }
        W2h[f * 64 + lane] = make_uint4(w4[0], w4[1], w4[2], w4[3]);
    }
}

// ---- main: 2048 blocks x 256 thr; block = (row i = bid>>1, half h = bid&1).
// R7: OCCUPANCY ATTACK. R0 ledger: unified VGPR+AGPR footprint in (102,128] ->
// floor(512/V) = 4 waves/SIMD hard cap; per-wave issue is only ~25% of a SIMD
// (matches scaled VALUBusy+MfmaUtil ~18%) -> main is occupancy-capped latency
// stall, which is why R5 depth (null) and R6 rotation (-2us) barely moved it.
// Fix: (1) drop the W[2][4] register copy (-32 VGPR): read each W2 fragment
// from LDS right before its MFMA (2 live frags, not 8). Footprint -> ~(70,96];
// __launch_bounds__(256,5) pins allocator <=102 -> 5 waves/SIMD. (2) half-row
// split (8 tiles/wave) so grid 2048 can actually FILL the 5th block slot/CU.
// Block writes Shalf[bid] (partial expsum over its 512 cols); diagonal owner
// plain-stores T0row[i]. Rotation (R6, now mod 8) kept. Zero atomics (R1),
// plain stores, 3 launches (R4: cooperative launch banned under graph capture).
// SPILL SIGNATURE to watch (R3): main in top-5 with FETCH+WRITE storm -> revert.
__global__ void __launch_bounds__(256, 5)
main_kernel(const unsigned short* __restrict__ Aph, const unsigned short* __restrict__ Bph,
            const uint4* __restrict__ W2h,
            const float* __restrict__ b2, const float* __restrict__ Wo,
            float* __restrict__ Shalf, float* __restrict__ T0row) {
    const int bid  = blockIdx.x;
    const int i    = bid >> 1;     // row
    const int hh   = bid & 1;      // half of the row
    const int rot  = bid & 7;
    const int tid  = threadIdx.x;
    const int lane = tid & 63;
    const int wave = tid >> 6;
    const int l15  = lane & 15;
    const int q    = lane >> 4;

    __shared__ uint4 sW[512];      // W2 frag bits, 8 KB (read per-tile, not copied)
    __shared__ float sb2[64];      // b2, 256 B
    __shared__ float sWo[64];      // Wo, 256 B
    __shared__ float sS[4];        // per-wave exp-sum partials

    // cooperative stage: 2 x 16B VMEM per thread + tiny b2/Wo copy
    sW[tid]       = W2h[tid];
    sW[tid + 256] = W2h[tid + 256];
    if (tid < 64)                  sb2[tid]      = b2[tid];
    else if (tid < 128)            sWo[tid - 64] = Wo[tid - 64];
    __syncthreads();

    // B_i per-lane slice (fp16 frag order): 2 dwordx4 = 16 halves, k = s*32+q*8+e
    H8U cb0, cb1;
    {
        const uint4* bp = (const uint4*)(Bph + i * 64 + q * 16);
        cb0.u = bp[0];
        cb1.u = bp[1];
    }

    // b2 folded into acc init; Wo per-lane, element (t,r) is h = t*16 + q*4 + r
    f32x4 b2v[4];
    float wov[4][4];
    #pragma unroll
    for (int t = 0; t < 4; ++t) {
        float4 bt = *(const float4*)(sb2 + t * 16 + q * 4);
        float4 wt = *(const float4*)(sWo + t * 16 + q * 4);
        b2v[t] = (f32x4){bt.x, bt.y, bt.z, bt.w};
        wov[t][0] = wt.x; wov[t][1] = wt.y; wov[t][2] = wt.z; wov[t][3] = wt.w;
    }

    const half8 zero = {0, 0, 0, 0, 0, 0, 0, 0};
    float sacc = 0.f;

    // Wave owns 8 tiles: physical tile for logical step t is tbase + ((t+rot)&7).
    const int tbase = hh * 32 + wave * 8;
    const unsigned short* ap = Aph + tbase * 1024 + lane * 16;

    // Prologue: logical steps 0 and 1 in flight.
    H8U xa0, xa1, xb0, xb1;
    {
        const uint4* p0 = (const uint4*)(ap + ((0 + rot) & 7) * 1024);
        xa0.u = p0[0];
        xa1.u = p0[1];
        const uint4* p1 = (const uint4*)(ap + ((1 + rot) & 7) * 1024);
        xb0.u = p1[0];
        xb1.u = p1[1];
    }

    #pragma unroll
    for (int t = 0; t < 8; t += 2) {
        // ---- even step t: consume xa, refill with step t+2
        {
            half8 a0 = __builtin_elementwise_max(xa0.h + cb0.h, zero);   // k 0..31
            half8 a1 = __builtin_elementwise_max(xa1.h + cb1.h, zero);   // k 32..63
            if (t + 2 < 8) {
                const uint4* nx = (const uint4*)(ap + ((t + 2 + rot) & 7) * 1024);
                xa0.u = nx[0];
                xa1.u = nx[1];
            }

            f32x4 acc[4];
            #pragma unroll
            for (int u = 0; u < 4; ++u) acc[u] = b2v[u];
            #pragma unroll
            for (int u = 0; u < 4; ++u) {
                H8U w0; w0.u = sW[u * 64 + lane];          // f = 0*4+u
                acc[u] = __builtin_amdgcn_mfma_f32_16x16x32_f16(w0.h, a0, acc[u], 0, 0, 0);
                H8U w1; w1.u = sW[(4 + u) * 64 + lane];    // f = 1*4+u
                acc[u] = __builtin_amdgcn_mfma_f32_16x16x32_f16(w1.h, a1, acc[u], 0, 0, 0);
            }

            float p0 = 0.f, p1 = 0.f, p2 = 0.f, p3 = 0.f;
            #pragma unroll
            for (int u = 0; u < 4; ++u) {
                p0 = fmaf(fmaxf(acc[u][0], 0.f), wov[u][0], p0);
                p1 = fmaf(fmaxf(acc[u][1], 0.f), wov[u][1], p1);
                p2 = fmaf(fmaxf(acc[u][2], 0.f), wov[u][2], p2);
                p3 = fmaf(fmaxf(acc[u][3], 0.f), wov[u][3], p3);
            }
            float ps = (p0 + p1) + (p2 + p3);
            ps += __shfl_xor(ps, 16);
            ps += __shfl_xor(ps, 32);   // T1[i,j], replicated over the 4 q-groups
            const int j = (tbase + ((t + rot) & 7)) * 16 + l15;
            if (j == i && q == 0) T0row[i] = ps;   // diagonal: one writer grid-wide
            sacc += __expf(ps);
        }
        // ---- odd step t+1: consume xb, refill with step t+3
        {
            half8 a0 = __builtin_elementwise_max(xb0.h + cb0.h, zero);
            half8 a1 = __builtin_elementwise_max(xb1.h + cb1.h, zero);
            if (t + 3 < 8) {
                const uint4* nx = (const uint4*)(ap + ((t + 3 + rot) & 7) * 1024);
                xb0.u = nx[0];
                xb1.u = nx[1];
            }

            f32x4 acc[4];
            #pragma unroll
            for (int u = 0; u < 4; ++u) acc[u] = b2v[u];
            #pragma unroll
            for (int u = 0; u < 4; ++u) {
                H8U w0; w0.u = sW[u * 64 + lane];
                acc[u] = __builtin_amdgcn_mfma_f32_16x16x32_f16(w0.h, a0, acc[u], 0, 0, 0);
                H8U w1; w1.u = sW[(4 + u) * 64 + lane];
                acc[u] = __builtin_amdgcn_mfma_f32_16x16x32_f16(w1.h, a1, acc[u], 0, 0, 0);
            }

            float p0 = 0.f, p1 = 0.f, p2 = 0.f, p3 = 0.f;
            #pragma unroll
            for (int u = 0; u < 4; ++u) {
                p0 = fmaf(fmaxf(acc[u][0], 0.f), wov[u][0], p0);
                p1 = fmaf(fmaxf(acc[u][1], 0.f), wov[u][1], p1);
                p2 = fmaf(fmaxf(acc[u][2], 0.f), wov[u][2], p2);
                p3 = fmaf(fmaxf(acc[u][3], 0.f), wov[u][3], p3);
            }
            float ps = (p0 + p1) + (p2 + p3);
            ps += __shfl_xor(ps, 16);
            ps += __shfl_xor(ps, 32);
            const int j = (tbase + ((t + 1 + rot) & 7)) * 16 + l15;
            if (j == i && q == 0) T0row[i] = ps;
            sacc += __expf(ps);
        }
    }

    // reduce over l15 only (q-groups are exact replicas -> exact sum)
    sacc += __shfl_xor(sacc, 1);
    sacc += __shfl_xor(sacc, 2);
    sacc += __shfl_xor(sacc, 4);
    sacc += __shfl_xor(sacc, 8);
    if (lane == 0) sS[wave] = sacc;
    __syncthreads();
    if (tid == 0)
        Shalf[bid] = (sS[0] + sS[1]) + (sS[2] + sS[3]);   // half-row expsum
}

// ---- combine: 1 block x 1024 thr. bound = mean(T0 - log S) + ln N
__global__ void __launch_bounds__(1024)
combine_finish(const float* __restrict__ Shalf, const float* __restrict__ T0row,
               float* __restrict__ out) {
    int i = threadIdx.x;
    float S = Shalf[2 * i] + Shalf[2 * i + 1];
    float c = T0row[i] - logf(S);
    #pragma unroll
    for (int off = 1; off < 64; off <<= 1) c += __shfl_xor(c, off);
    __shared__ float sc[16];
    int w = threadIdx.x >> 6;
    if ((threadIdx.x & 63) == 0) sc[w] = c;
    __syncthreads();
    if (threadIdx.x == 0) {
        float C = 0.f;
        #pragma unroll
        for (int k = 0; k < 16; ++k) C += sc[k];
        out[0] = C * (1.0f / 1024.0f) + 6.9314718055994531f;   // + ln 1024
    }
}

extern "C" void kernel_launch(void* const* d_in, const int* in_sizes, int n_in,
                              void* d_out, int out_size, void* d_ws, size_t ws_size,
                              hipStream_t stream) {
    const float* z_c = (const float*)d_in[0];
    const float* z_d = (const float*)d_in[1];
    const float* W1  = (const float*)d_in[2];
    const float* b1  = (const float*)d_in[3];
    const float* W2  = (const float*)d_in[4];
    const float* b2  = (const float*)d_in[5];
    const float* Wo  = (const float*)d_in[6];
    // d_in[7] = bo: shifts T0.mean and every LSE equally -> cancels; omitted.
    float* out   = (float*)d_out;

    unsigned short* Aph = (unsigned short*)d_ws;   // 65536 fp16 (128 KB), frag-order
    unsigned short* Bph = Aph + NN * 64;           // 65536 fp16 (128 KB), frag-order
    uint4* W2h   = (uint4*)(Bph + NN * 64);        // 512 uint4 (8 KB)
    float* Shalf = (float*)(W2h + 512);            // 2048 fp32 (plain-stored)
    float* T0row = Shalf + 2 * NN;                 // 1024 fp32 (plain-stored)

    prep_kernel<<<514, 256, 0, stream>>>(z_c, z_d, W1, b1, W2, Aph, Bph, W2h);
    main_kernel<<<2048, 256, 0, stream>>>(Aph, Bph, W2h, b2, Wo, Shalf, T0row);
    combine_finish<<<1, 1024, 0, stream>>>(Shalf, T0row, out);
}

// Round 8
// 85.199 us; speedup vs baseline: 1.8578x; 1.8578x over previous
//
#include <hip/hip_runtime.h>
#include <hip/hip_fp16.h>
#include <math.h>

#define NN 1024

typedef _Float16 half8 __attribute__((ext_vector_type(8)));
typedef float f32x4 __attribute__((ext_vector_type(4)));

union H8U { uint4 u; half8 h; };

__device__ __forceinline__ unsigned short h_bits(float x) {
    _Float16 h = (_Float16)x;          // RNE
    unsigned short b;
    __builtin_memcpy(&b, &h, 2);
    return b;
}

// ---- prep: blocks [0,512): A' = z_c@W1c + b1 -> fp16 frag-order Aph;
//            B = z_d@W1d -> fp16 frag-order Bph.
//            blocks [512,514): W2 -> fp16 MFMA frag layout W2h.
__global__ void prep_kernel(const float* __restrict__ z_c, const float* __restrict__ z_d,
                            const float* __restrict__ W1, const float* __restrict__ b1,
                            const float* __restrict__ W2,
                            unsigned short* __restrict__ Aph,
                            unsigned short* __restrict__ Bph,
                            uint4* __restrict__ W2h) {
    if (blockIdx.x < 512) {
        int t = blockIdx.x * 256 + threadIdx.x;
        int sel = t >> 16;            // 0 -> A', 1 -> B
        int idx = t & 0xffff;
        int n = idx >> 6, h = idx & 63;
        const float* z = (sel ? z_d : z_c) + n * 64;
        const float* w = W1 + (sel ? 4096 : 0) + h;   // W1 (128,64) row-major
        float a0 = sel ? 0.f : b1[h], a1 = 0.f;
        #pragma unroll
        for (int k = 0; k < 64; k += 2) {
            a0 = fmaf(z[k],     w[k * 64],       a0);
            a1 = fmaf(z[k + 1], w[(k + 1) * 64], a1);
        }
        unsigned short val = h_bits(a0 + a1);   // fp32-exact matmul, one RNE to fp16
        int s = h >> 5, q = (h >> 3) & 3, e = h & 7;
        if (sel) {
            Bph[n * 64 + q * 16 + s * 8 + e] = val;
        } else {
            Aph[(n >> 4) * 1024 + (q * 16 + (n & 15)) * 16 + s * 8 + e] = val;
        }
    } else {
        int tt = (blockIdx.x - 512) * 256 + threadIdx.x;   // 0..511
        int f = tt >> 6, lane = tt & 63;                   // f = s*4 + t, 8 frags
        int s = f >> 2, t4 = f & 3, q = lane >> 4, l15 = lane & 15;
        int n = t4 * 16 + l15;
        unsigned w4[4];
        #pragma unroll
        for (int p = 0; p < 4; ++p) {
            int k = s * 32 + q * 8 + 2 * p;
            unsigned lo = h_bits(W2[k * 64 + n]);
            unsigned hi = h_bits(W2[(k + 1) * 64 + n]);
            w4[p] = lo | (hi << 16);
        }
        W2h[f * 64 + lane] = make_uint4(w4[0], w4[1], w4[2], w4[3]);
    }
}

// ---- main: 2048 blocks x 256 thr; block = (row i = bid>>1, half hh = bid&1),
// 8 tiles/wave. R8: HALF-ROW SPLIT AT THE PROVEN REGISTER CONFIG. R7 bundled
// this split with a (256,5) pin that spilled (FETCH+WRITE 303MB: the 8 sW reads
// are loop-invariant -> compiler re-hoisted them into registers and spilled;
// source-level shaving of loop-invariant state is DEFEATED by the unroller).
// Here: W[2][4] stays in registers, __launch_bounds__(256,4), footprint
// byte-identical to R6's proven-fit (102,128]. The split's mechanism: two
// GENERATIONS of blocks per CU -> block k+1's prologue overlaps block k's
// epilogue (previously all-lockstep), and per-block serial chain halves.
// Rotation (R6, -2us confirmed): rot = bid&7; same-CU co-residents (bid+-256,
// 256==0 mod 8) share rot -> L1 sharing preserved.
// R5: prefetch depth beyond the unroller's own schedule is NULL.
// R4: hipLaunchCooperativeKernel fails SILENTLY under graph capture. BANNED.
// R1: grid-scale same-address atomics are poison. Plain stores only.
// __launch_bounds__(256, 4) is LOAD-BEARING. Do not raise. Do not grow state.
__global__ void __launch_bounds__(256, 4)
main_kernel(const unsigned short* __restrict__ Aph, const unsigned short* __restrict__ Bph,
            const uint4* __restrict__ W2h,
            const float* __restrict__ b2, const float* __restrict__ Wo,
            float* __restrict__ Shalf, float* __restrict__ T0row) {
    const int bid  = blockIdx.x;
    const int i    = bid >> 1;     // row
    const int hh   = bid & 1;      // half of the row
    const int rot  = bid & 7;
    const int tid  = threadIdx.x;
    const int lane = tid & 63;
    const int wave = tid >> 6;
    const int l15  = lane & 15;
    const int q    = lane >> 4;

    __shared__ uint4 sW[512];      // W2 frag bits, 8 KB
    __shared__ float sb2[64];      // b2, 256 B
    __shared__ float sWo[64];      // Wo, 256 B
    __shared__ float sS[4];        // per-wave exp-sum partials

    // cooperative stage: 2 x 16B VMEM per thread + tiny b2/Wo copy
    sW[tid]       = W2h[tid];
    sW[tid + 256] = W2h[tid + 256];
    if (tid < 64)                  sb2[tid]      = b2[tid];
    else if (tid < 128)            sWo[tid - 64] = Wo[tid - 64];
    __syncthreads();

    // W2 fragments from LDS: 8 ds_read_b128, lane-contiguous (conflict-free)
    half8 W[2][4];   // [s][t]
    #pragma unroll
    for (int f = 0; f < 8; ++f) {
        H8U u; u.u = sW[f * 64 + lane];
        W[f >> 2][f & 3] = u.h;
    }

    // B_i per-lane slice (fp16 frag order): 2 dwordx4 = 16 halves, k = s*32+q*8+e
    H8U cb0, cb1;
    {
        const uint4* bp = (const uint4*)(Bph + i * 64 + q * 16);
        cb0.u = bp[0];
        cb1.u = bp[1];
    }

    // b2 folded into acc init; Wo per-lane, element (t,r) is h = t*16 + q*4 + r
    f32x4 b2v[4];
    float wov[4][4];
    #pragma unroll
    for (int t = 0; t < 4; ++t) {
        float4 bt = *(const float4*)(sb2 + t * 16 + q * 4);
        float4 wt = *(const float4*)(sWo + t * 16 + q * 4);
        b2v[t] = (f32x4){bt.x, bt.y, bt.z, bt.w};
        wov[t][0] = wt.x; wov[t][1] = wt.y; wov[t][2] = wt.z; wov[t][3] = wt.w;
    }

    const half8 zero = {0, 0, 0, 0, 0, 0, 0, 0};
    float sacc = 0.f;

    // Wave owns 8 tiles: physical tile for logical step t is tbase + ((t+rot)&7).
    const int tbase = hh * 32 + wave * 8;
    const unsigned short* ap = Aph + tbase * 1024 + lane * 16;

    // Prologue: logical steps 0 and 1 in flight.
    H8U xa0, xa1, xb0, xb1;
    {
        const uint4* p0 = (const uint4*)(ap + ((0 + rot) & 7) * 1024);
        xa0.u = p0[0];
        xa1.u = p0[1];
        const uint4* p1 = (const uint4*)(ap + ((1 + rot) & 7) * 1024);
        xb0.u = p1[0];
        xb1.u = p1[1];
    }

    #pragma unroll
    for (int t = 0; t < 8; t += 2) {
        // ---- even step t: consume xa, refill with step t+2
        {
            half8 a0 = __builtin_elementwise_max(xa0.h + cb0.h, zero);   // k 0..31
            half8 a1 = __builtin_elementwise_max(xa1.h + cb1.h, zero);   // k 32..63
            if (t + 2 < 8) {
                const uint4* nx = (const uint4*)(ap + ((t + 2 + rot) & 7) * 1024);
                xa0.u = nx[0];
                xa1.u = nx[1];
            }

            f32x4 acc[4];
            #pragma unroll
            for (int u = 0; u < 4; ++u) acc[u] = b2v[u];
            #pragma unroll
            for (int u = 0; u < 4; ++u) {
                acc[u] = __builtin_amdgcn_mfma_f32_16x16x32_f16(W[0][u], a0, acc[u], 0, 0, 0);
                acc[u] = __builtin_amdgcn_mfma_f32_16x16x32_f16(W[1][u], a1, acc[u], 0, 0, 0);
            }

            float p0 = 0.f, p1 = 0.f, p2 = 0.f, p3 = 0.f;
            #pragma unroll
            for (int u = 0; u < 4; ++u) {
                p0 = fmaf(fmaxf(acc[u][0], 0.f), wov[u][0], p0);
                p1 = fmaf(fmaxf(acc[u][1], 0.f), wov[u][1], p1);
                p2 = fmaf(fmaxf(acc[u][2], 0.f), wov[u][2], p2);
                p3 = fmaf(fmaxf(acc[u][3], 0.f), wov[u][3], p3);
            }
            float ps = (p0 + p1) + (p2 + p3);
            ps += __shfl_xor(ps, 16);
            ps += __shfl_xor(ps, 32);   // T1[i,j], replicated over the 4 q-groups
            const int j = (tbase + ((t + rot) & 7)) * 16 + l15;
            if (j == i && q == 0) T0row[i] = ps;   // diagonal: one writer grid-wide
            sacc += __expf(ps);
        }
        // ---- odd step t+1: consume xb, refill with step t+3
        {
            half8 a0 = __builtin_elementwise_max(xb0.h + cb0.h, zero);
            half8 a1 = __builtin_elementwise_max(xb1.h + cb1.h, zero);
            if (t + 3 < 8) {
                const uint4* nx = (const uint4*)(ap + ((t + 3 + rot) & 7) * 1024);
                xb0.u = nx[0];
                xb1.u = nx[1];
            }

            f32x4 acc[4];
            #pragma unroll
            for (int u = 0; u < 4; ++u) acc[u] = b2v[u];
            #pragma unroll
            for (int u = 0; u < 4; ++u) {
                acc[u] = __builtin_amdgcn_mfma_f32_16x16x32_f16(W[0][u], a0, acc[u], 0, 0, 0);
                acc[u] = __builtin_amdgcn_mfma_f32_16x16x32_f16(W[1][u], a1, acc[u], 0, 0, 0);
            }

            float p0 = 0.f, p1 = 0.f, p2 = 0.f, p3 = 0.f;
            #pragma unroll
            for (int u = 0; u < 4; ++u) {
                p0 = fmaf(fmaxf(acc[u][0], 0.f), wov[u][0], p0);
                p1 = fmaf(fmaxf(acc[u][1], 0.f), wov[u][1], p1);
                p2 = fmaf(fmaxf(acc[u][2], 0.f), wov[u][2], p2);
                p3 = fmaf(fmaxf(acc[u][3], 0.f), wov[u][3], p3);
            }
            float ps = (p0 + p1) + (p2 + p3);
            ps += __shfl_xor(ps, 16);
            ps += __shfl_xor(ps, 32);
            const int j = (tbase + ((t + 1 + rot) & 7)) * 16 + l15;
            if (j == i && q == 0) T0row[i] = ps;
            sacc += __expf(ps);
        }
    }

    // reduce over l15 only (q-groups are exact replicas -> exact sum)
    sacc += __shfl_xor(sacc, 1);
    sacc += __shfl_xor(sacc, 2);
    sacc += __shfl_xor(sacc, 4);
    sacc += __shfl_xor(sacc, 8);
    if (lane == 0) sS[wave] = sacc;
    __syncthreads();
    if (tid == 0)
        Shalf[bid] = (sS[0] + sS[1]) + (sS[2] + sS[3]);   // half-row expsum
}

// ---- combine: 1 block x 1024 thr. bound = mean(T0 - log S) + ln N
__global__ void __launch_bounds__(1024)
combine_finish(const float* __restrict__ Shalf, const float* __restrict__ T0row,
               float* __restrict__ out) {
    int i = threadIdx.x;
    float S = Shalf[2 * i] + Shalf[2 * i + 1];
    float c = T0row[i] - logf(S);
    #pragma unroll
    for (int off = 1; off < 64; off <<= 1) c += __shfl_xor(c, off);
    __shared__ float sc[16];
    int w = threadIdx.x >> 6;
    if ((threadIdx.x & 63) == 0) sc[w] = c;
    __syncthreads();
    if (threadIdx.x == 0) {
        float C = 0.f;
        #pragma unroll
        for (int k = 0; k < 16; ++k) C += sc[k];
        out[0] = C * (1.0f / 1024.0f) + 6.9314718055994531f;   // + ln 1024
    }
}

extern "C" void kernel_launch(void* const* d_in, const int* in_sizes, int n_in,
                              void* d_out, int out_size, void* d_ws, size_t ws_size,
                              hipStream_t stream) {
    const float* z_c = (const float*)d_in[0];
    const float* z_d = (const float*)d_in[1];
    const float* W1  = (const float*)d_in[2];
    const float* b1  = (const float*)d_in[3];
    const float* W2  = (const float*)d_in[4];
    const float* b2  = (const float*)d_in[5];
    const float* Wo  = (const float*)d_in[6];
    // d_in[7] = bo: shifts T0.mean and every LSE equally -> cancels; omitted.
    float* out   = (float*)d_out;

    unsigned short* Aph = (unsigned short*)d_ws;   // 65536 fp16 (128 KB), frag-order
    unsigned short* Bph = Aph + NN * 64;           // 65536 fp16 (128 KB), frag-order
    uint4* W2h   = (uint4*)(Bph + NN * 64);        // 512 uint4 (8 KB)
    float* Shalf = (float*)(W2h + 512);            // 2048 fp32 (plain-stored)
    float* T0row = Shalf + 2 * NN;                 // 1024 fp32 (plain-stored)

    prep_kernel<<<514, 256, 0, stream>>>(z_c, z_d, W1, b1, W2, Aph, Bph, W2h);
    main_kernel<<<2048, 256, 0, stream>>>(Aph, Bph, W2h, b2, Wo, Shalf, T0row);
    combine_finish<<<1, 1024, 0, stream>>>(Shalf, T0row, out);
}